// Round 4
// baseline (280.171 us; speedup 1.0000x reference)
//
#include <hip/hip_runtime.h>

// ---------------------------------------------------------------------------
// TemporalHyperedge: loss[b] = 0.2 * sum_n ||cur[b]@r_proj - W@pre[b]||_2
//                              + sum_n (max_m W[n,m] + 0.001*||W[n,:]||_2)
// W = incidence_m masked to > 0.01. Output = [loss(32) , incidence_m(2048^2)].
//
// R8 change: gemm_diff wave tile 64x64 -> 128x64 (8 waves, 512 thr,
// acc[4][2]). Cycle accounting shows the LDS read pipe is the wall
// (~110k cyc reads vs 73.7k MFMA vs 206k total); FLOP/LDS-byte is
// WM*WN/(WM+WN): 32 -> 42.7, cutting block reads 128 -> 96 b128/tile.
// Depth-3 counted-vmcnt rotation kept verbatim (4 GLL16/wave/tile,
// steady vmcnt(8), drain at t=70/71). prep/finalize identical to R7.
// ---------------------------------------------------------------------------

typedef __attribute__((ext_vector_type(8))) short bf16x8;
typedef __attribute__((ext_vector_type(8))) unsigned short ushort8;
typedef __attribute__((ext_vector_type(16))) float f32x16;

__device__ __forceinline__ unsigned short f2bf(float f) {
    union { float f; unsigned u; } x; x.f = f;
    unsigned r = x.u + 0x7fffu + ((x.u >> 16) & 1u);   // RNE
    return (unsigned short)(r >> 16);
}

#define GLL16(g, l)                                                         \
    __builtin_amdgcn_global_load_lds(                                       \
        (const __attribute__((address_space(1))) void*)(g),                 \
        (__attribute__((address_space(3))) void*)(l), 16, 0, 0)

// --------------------------------------------------------------------------
// transpose_64x64: src f32 (R,C) tile (r0,c0) -> dst bf16 (C,R).
// --------------------------------------------------------------------------
__device__ __forceinline__ void transpose_64x64(
    const float* __restrict__ src, unsigned short* __restrict__ dst,
    int R, int C, int r0, int c0, unsigned short* __restrict__ tile) {
    const int t = threadIdx.x;
    const int fr = t >> 4, fc = (t & 15) * 4;
#pragma unroll
    for (int it = 0; it < 4; ++it) {
        int m = fr + it * 16;
        float4 v = *(const float4*)(src + (size_t)(r0 + m) * C + c0 + fc);
        tile[(fc + 0) * 68 + m] = f2bf(v.x);
        tile[(fc + 1) * 68 + m] = f2bf(v.y);
        tile[(fc + 2) * 68 + m] = f2bf(v.z);
        tile[(fc + 3) * 68 + m] = f2bf(v.w);
    }
    __syncthreads();
    const int d = t >> 2, m0 = (t & 3) * 16;
    unsigned short v[16];
#pragma unroll
    for (int j = 0; j < 4; ++j)
        *(ushort4*)(v + j * 4) = *(const ushort4*)(tile + d * 68 + m0 + j * 4);
    unsigned short* dp = dst + (size_t)(c0 + d) * R + r0 + m0;
    ushort8 p0, p1;
#pragma unroll
    for (int j = 0; j < 8; ++j) { p0[j] = v[j]; p1[j] = v[8 + j]; }
    *(ushort8*)(dp) = p0;
    *(ushort8*)(dp + 8) = p1;
}

// --------------------------------------------------------------------------
// prep_inc: incidence rows: copy-out, -masked bf16 W, crow[row]=l1+1e-3*l2
// --------------------------------------------------------------------------
__global__ __launch_bounds__(256) void prep_inc(
    const float* __restrict__ inc, float* __restrict__ out_inc,
    unsigned short* __restrict__ Wneg, float* __restrict__ crow) {
    __shared__ float smax[4], ssum[4];
    const int row = blockIdx.x;
    const int t = threadIdx.x;
    const float4* src = (const float4*)(inc + (size_t)row * 2048);
    float4* dst = (float4*)(out_inc + (size_t)row * 2048);
    ushort4* wp = (ushort4*)(Wneg + (size_t)row * 2048);
    float lmax = 0.f, ss = 0.f;
#pragma unroll
    for (int it = 0; it < 2; ++it) {
        int i = it * 256 + t;
        float4 v = src[i];
        dst[i] = v;
        float w0 = v.x > 0.01f ? v.x : 0.f;
        float w1 = v.y > 0.01f ? v.y : 0.f;
        float w2 = v.z > 0.01f ? v.z : 0.f;
        float w3 = v.w > 0.01f ? v.w : 0.f;
        ushort4 p;
        p.x = f2bf(-w0); p.y = f2bf(-w1); p.z = f2bf(-w2); p.w = f2bf(-w3);
        wp[i] = p;
        lmax = fmaxf(lmax, fmaxf(fmaxf(w0, w1), fmaxf(w2, w3)));
        ss += w0 * w0 + w1 * w1 + w2 * w2 + w3 * w3;
    }
#pragma unroll
    for (int off = 32; off; off >>= 1) {
        lmax = fmaxf(lmax, __shfl_down(lmax, off));
        ss += __shfl_down(ss, off);
    }
    int wv = t >> 6, ln = t & 63;
    if (ln == 0) { smax[wv] = lmax; ssum[wv] = ss; }
    __syncthreads();
    if (t == 0) {
        float m = fmaxf(fmaxf(smax[0], smax[1]), fmaxf(smax[2], smax[3]));
        float s = ssum[0] + ssum[1] + ssum[2] + ssum[3];
        crow[row] = m + 0.001f * sqrtf(s);
    }
}

// --------------------------------------------------------------------------
// prep_tr: [0,4096)      pre (32,2048,256) -> preT (32,256,2048) bf16
//          [4096,4112)   r_proj (256,256) -> rprojT bf16 transpose
//          [4112,6160)   cur f32 -> curbf bf16 (same layout, no transpose)
// --------------------------------------------------------------------------
__global__ __launch_bounds__(256) void prep_tr(
    const float* __restrict__ pre, unsigned short* __restrict__ preT,
    const float* __restrict__ r_proj, unsigned short* __restrict__ rprojT,
    const float* __restrict__ cur, unsigned short* __restrict__ curbf) {
    __shared__ unsigned short tile[64 * 68];
    const int bid = blockIdx.x;
    const int t = threadIdx.x;
    if (bid < 4096) {
        const int b = bid >> 7;
        const int mt = (bid & 127) >> 2;
        const int dt = bid & 3;
        transpose_64x64(pre + (size_t)b * 524288, preT + (size_t)b * 524288,
                        2048, 256, mt * 64, dt * 64, tile);
    } else if (bid < 4112) {
        const int tt = bid - 4096;
        transpose_64x64(r_proj, rprojT, 256, 256, (tt >> 2) * 64, (tt & 3) * 64,
                        tile);
    } else {
        // cur -> bf16: 2048 blocks x 256 thr x 32 f32 = 16.78M elems
        const size_t base = (size_t)(bid - 4112) * 8192;
#pragma unroll
        for (int i = 0; i < 8; ++i) {
            size_t idx = base + (size_t)(i * 256 + t) * 4;
            float4 v = *(const float4*)(cur + idx);
            ushort4 p;
            p.x = f2bf(v.x); p.y = f2bf(v.y); p.z = f2bf(v.z); p.w = f2bf(v.w);
            *(ushort4*)(curbf + idx) = p;
        }
    }
}

// --------------------------------------------------------------------------
// gemm_diff: block = 256n x 256d, BK=32, 72 K-tiles (64 Wneg/preT + 8
// curbf/rprojT). 32x32x16 MFMA, 8 waves (2m x 4n), wave tile 128x64
// (acc f32x16[4][2] = 128 regs; 42.7 FLOP per LDS byte vs 32 at 64x64).
//
// LDS: 4-deep rotation, per tile A(16KB)+B(16KB) -> 128KB total.
// Swizzle (64B rows = 4 x 16B chunks): LDS[r][p] = G[r][p ^ ((r>>1)&3)];
// staged via source-side chunk permute, unswizzled on fragment read.
//
// Pipeline: 3 tiles (12 loads/wave) always in flight. Per tile t:
//   s_waitcnt vmcnt(8)   [tile t landed; t+1, t+2 remain in flight]
//   s_barrier            [all waves' DMA visible; WAR on buf[(t+3)&3] closed]
//   stage(t+3)           [4 GLL16/wave into buf[(t+3)&3]]
//   ks-loop on buf[t&3]  [2 ks x (4 A + 2 B b128 reads + 8 MFMA) per wave]
// Drain only at t=70 (vmcnt 4) and t=71 (vmcnt 0).
// --------------------------------------------------------------------------
__global__ __launch_bounds__(512, 2) void gemm_diff(
    const unsigned short* __restrict__ Wneg,    // (2048,2048) bf16 neg+masked
    const unsigned short* __restrict__ curbf,   // (32,2048,256) bf16
    const unsigned short* __restrict__ preT,    // (32,256,2048) bf16
    const unsigned short* __restrict__ rprojT,  // (256,256) bf16
    float* __restrict__ Ssq)                    // (32,2048)
{
    const int n0 = blockIdx.x * 256;
    const int b  = blockIdx.y;

    __shared__ unsigned short Ab[4 * 256 * 32];  // 64 KB
    __shared__ unsigned short Bb[4 * 256 * 32];  // 64 KB
    __shared__ float ssq[256];

    const int tid  = threadIdx.x;
    const int w    = tid >> 6;                   // 0..7
    const int lane = tid & 63;
    const int l32  = lane & 31;
    const int half = lane >> 5;
    const int wm   = w >> 2;                     // 0..1 (n-band of 128)
    const int wn   = w & 3;                      // 0..3 (d-band of 64)
    const int w32  = w * 32;
    const int srow  = lane >> 2;                 // staging row within 16
    const int sbyte = ((lane & 3) ^ ((lane >> 3) & 3)) * 16;  // swizzled src
    const int q2    = (l32 >> 1) & 3;            // read-side swizzle

    if (tid < 256) ssq[tid] = 0.f;

    f32x16 acc[4][2] = {};

    const unsigned short* curA = curbf + (size_t)b * 2048 * 256 + (size_t)n0 * 256;
    const unsigned short* preB = preT + (size_t)b * 256 * 2048;
    const unsigned short* An   = Wneg + (size_t)n0 * 2048;

    // stage tile T (A 256x32 + B 256x32): 2+2 GLL16 per wave (rows w*32..+31)
#define STAGEPAIR(T, AB, AS, BB, BS, KK)                                       \
    {                                                                          \
        _Pragma("unroll") for (int p = 0; p < 2; ++p) {                        \
            const int rowb = w32 + p * 16;                                     \
            GLL16((const char*)((AB) + (size_t)(rowb + srow) * (AS) + (KK)) + sbyte,\
                  (char*)Ab + ((T) & 3) * 16384 + rowb * 64);                  \
            GLL16((const char*)((BB) + (size_t)(rowb + srow) * (BS) + (KK)) + sbyte,\
                  (char*)Bb + ((T) & 3) * 16384 + rowb * 64);                  \
        }                                                                      \
    }

    // ---- prologue: tiles 0,1,2 in flight (12 loads/wave)
    STAGEPAIR(0, An, 2048, preB, 2048, 0);
    STAGEPAIR(1, An, 2048, preB, 2048, 32);
    STAGEPAIR(2, An, 2048, preB, 2048, 64);

    for (int t = 0; t < 72; ++t) {
        if (t < 70)       asm volatile("s_waitcnt vmcnt(8)" ::: "memory");
        else if (t == 70) asm volatile("s_waitcnt vmcnt(4)" ::: "memory");
        else              asm volatile("s_waitcnt vmcnt(0)" ::: "memory");
        asm volatile("s_barrier" ::: "memory");

        if (t < 69) {
            const int t3 = t + 3;
            const unsigned short *aB, *bB;
            int aS, bS, kk;
            if (t3 < 64) { aB = An;   aS = 2048; bB = preB;   bS = 2048; kk = t3 * 32; }
            else         { aB = curA; aS = 256;  bB = rprojT; bS = 256;  kk = (t3 - 64) * 32; }
            STAGEPAIR(t3, aB, aS, bB, bS, kk);
        }

        const unsigned short* Ac = Ab + (t & 3) * 8192;
        const unsigned short* Bc = Bb + (t & 3) * 8192;
#pragma unroll
        for (int ks = 0; ks < 2; ++ks) {
            const int co = (((ks << 1) + half) ^ q2) << 3;
            bf16x8 af[4], bfr[2];
#pragma unroll
            for (int mi = 0; mi < 4; ++mi)
                af[mi] = *(const bf16x8*)(Ac + (wm * 128 + mi * 32 + l32) * 32 + co);
#pragma unroll
            for (int ni = 0; ni < 2; ++ni)
                bfr[ni] = *(const bf16x8*)(Bc + (wn * 64 + ni * 32 + l32) * 32 + co);
#pragma unroll
            for (int mi = 0; mi < 4; ++mi)
#pragma unroll
                for (int ni = 0; ni < 2; ++ni)
                    acc[mi][ni] = __builtin_amdgcn_mfma_f32_32x32x16_bf16(
                        af[mi], bfr[ni], acc[mi][ni], 0, 0, 0);
        }
    }
    __syncthreads();

    // 32x32 C/D layout: col(d)=lane&31, row(n)=(reg&3)+8*(reg>>2)+4*half
#pragma unroll
    for (int mi = 0; mi < 4; ++mi)
#pragma unroll
        for (int reg = 0; reg < 16; ++reg) {
            float s = 0.f;
#pragma unroll
            for (int ni = 0; ni < 2; ++ni) {
                float v = acc[mi][ni][reg];
                s += v * v;
            }
            s += __shfl_xor(s, 1);
            s += __shfl_xor(s, 2);
            s += __shfl_xor(s, 4);
            s += __shfl_xor(s, 8);
            s += __shfl_xor(s, 16);
            if (l32 == 0) {
                const int row = wm * 128 + mi * 32 +
                                (reg & 3) + 8 * (reg >> 2) + 4 * half;
                atomicAdd(&ssq[row], s);  // 4-way (wn)
            }
        }
    __syncthreads();
    if (tid < 256)
        Ssq[(size_t)b * 2048 + n0 + tid] = sqrtf(ssq[tid]);
}

// --------------------------------------------------------------------------
// finalize: loss[b] = 0.2 * sum_n Ssq[b,n] + sum_n crow[n]
// --------------------------------------------------------------------------
__global__ void finalize(const float* __restrict__ Ssq,
                         const float* __restrict__ crow,
                         float* __restrict__ out) {
    const int b = blockIdx.x;
    float s1 = 0.f, s2 = 0.f;
    for (int i = threadIdx.x; i < 2048; i += 256) {
        s1 += Ssq[(size_t)b * 2048 + i];
        s2 += crow[i];
    }
#pragma unroll
    for (int off = 32; off; off >>= 1) {
        s1 += __shfl_down(s1, off);
        s2 += __shfl_down(s2, off);
    }
    __shared__ float sm1[4], sm2[4];
    int wv = threadIdx.x >> 6, ln = threadIdx.x & 63;
    if (ln == 0) { sm1[wv] = s1; sm2[wv] = s2; }
    __syncthreads();
    if (threadIdx.x == 0)
        out[b] = 0.2f * (sm1[0] + sm1[1] + sm1[2] + sm1[3])
               + (sm2[0] + sm2[1] + sm2[2] + sm2[3]);
}

// --------------------------------------------------------------------------
extern "C" void kernel_launch(void* const* d_in, const int* in_sizes, int n_in,
                              void* d_out, int out_size, void* d_ws, size_t ws_size,
                              hipStream_t stream) {
    const float* cur    = (const float*)d_in[0];  // (32,2048,256)
    const float* pre    = (const float*)d_in[1];  // (32,2048,256)
    const float* r_proj = (const float*)d_in[2];  // (256,256)
    const float* inc    = (const float*)d_in[3];  // (2048,2048)
    float* out = (float*)d_out;                   // [0..31]=loss, [32..]=incidence

    char* ws = (char*)d_ws;
    unsigned short* Wneg   = (unsigned short*)(ws + 0);          //  8 MB
    unsigned short* preT   = (unsigned short*)(ws + 8388608);    // 32 MB
    unsigned short* rprojT = (unsigned short*)(ws + 41943040);   // 128 KB
    float*          Sbuf   = (float*)(ws + 42074112);            // 256 KB
    float*          crow   = (float*)(ws + 42336256);            // 8 KB
    unsigned short* curbf  = (unsigned short*)(ws + 42344448);   // 16 MB

    prep_inc<<<2048, 256, 0, stream>>>(inc, out + 32, Wneg, crow);
    prep_tr<<<6160, 256, 0, stream>>>(pre, preT, r_proj, rprojT, cur, curbf);
    gemm_diff<<<dim3(8, 32), 512, 0, stream>>>(Wneg, curbf, preT, rprojT, Sbuf);
    finalize<<<32, 256, 0, stream>>>(Sbuf, crow, out);
}

// Round 5
// 258.234 us; speedup vs baseline: 1.0849x; 1.0849x over previous
//
#include <hip/hip_runtime.h>

// ---------------------------------------------------------------------------
// TemporalHyperedge: loss[b] = 0.2 * sum_n ||cur[b]@r_proj - W@pre[b]||_2
//                              + sum_n (max_m W[n,m] + 0.001*||W[n,:]||_2)
// W = incidence_m masked to > 0.01. Output = [loss(32) , incidence_m(2048^2)].
//
// R9 changes (gemm core = R7 verbatim, the best measured at 98 us):
// 1) XCD-aware flat-grid remap: xcd=i&7, slot=i>>3, panel=slot&7,
//    batch=xcd+8*(slot>>3). Each XCD: 8 panels x 4 batches; panels of one
//    batch adjacent -> preT tile fetched once per XCD (dup 8x -> 1x).
//    Fetch demand ~152 -> ~130 MB (invariant: fetch/dur ~1.6 TB/s in
//    R4-R8 across all schedules -> bytes are the lever).
// 2) prep_inc+prep_tr merged into prep_all (R0 evidence: split cost ~20us).
// 3) finalize folded into gemm epilogue (atomicAdd per-panel partials into
//    out[b]; prep_all zeroes out[0..31]). 4 launches -> 2.
// ---------------------------------------------------------------------------

typedef __attribute__((ext_vector_type(8))) short bf16x8;
typedef __attribute__((ext_vector_type(8))) unsigned short ushort8;
typedef __attribute__((ext_vector_type(16))) float f32x16;

__device__ __forceinline__ unsigned short f2bf(float f) {
    union { float f; unsigned u; } x; x.f = f;
    unsigned r = x.u + 0x7fffu + ((x.u >> 16) & 1u);   // RNE
    return (unsigned short)(r >> 16);
}

#define GLL16(g, l)                                                         \
    __builtin_amdgcn_global_load_lds(                                       \
        (const __attribute__((address_space(1))) void*)(g),                 \
        (__attribute__((address_space(3))) void*)(l), 16, 0, 0)

// --------------------------------------------------------------------------
// transpose_64x64: src f32 (R,C) tile (r0,c0) -> dst bf16 (C,R).
// --------------------------------------------------------------------------
__device__ __forceinline__ void transpose_64x64(
    const float* __restrict__ src, unsigned short* __restrict__ dst,
    int R, int C, int r0, int c0, unsigned short* __restrict__ tile) {
    const int t = threadIdx.x;
    const int fr = t >> 4, fc = (t & 15) * 4;
#pragma unroll
    for (int it = 0; it < 4; ++it) {
        int m = fr + it * 16;
        float4 v = *(const float4*)(src + (size_t)(r0 + m) * C + c0 + fc);
        tile[(fc + 0) * 68 + m] = f2bf(v.x);
        tile[(fc + 1) * 68 + m] = f2bf(v.y);
        tile[(fc + 2) * 68 + m] = f2bf(v.z);
        tile[(fc + 3) * 68 + m] = f2bf(v.w);
    }
    __syncthreads();
    const int d = t >> 2, m0 = (t & 3) * 16;
    unsigned short v[16];
#pragma unroll
    for (int j = 0; j < 4; ++j)
        *(ushort4*)(v + j * 4) = *(const ushort4*)(tile + d * 68 + m0 + j * 4);
    unsigned short* dp = dst + (size_t)(c0 + d) * R + r0 + m0;
    ushort8 p0, p1;
#pragma unroll
    for (int j = 0; j < 8; ++j) { p0[j] = v[j]; p1[j] = v[8 + j]; }
    *(ushort8*)(dp) = p0;
    *(ushort8*)(dp + 8) = p1;
}

// --------------------------------------------------------------------------
// prep_all — block sections:
//   [0,2048)     : incidence row: copy-out, -masked bf16 W, crow=l1+1e-3*l2
//                  (block 0 also zeroes out_loss[0..31])
//   [2048,6144)  : pre (32,2048,256) -> preT (32,256,2048) bf16 transpose
//   [6144,6160)  : r_proj (256,256) -> rprojT bf16 transpose
//   [6160,8208)  : cur f32 -> curbf bf16 (same layout)
// --------------------------------------------------------------------------
__global__ __launch_bounds__(256) void prep_all(
    const float* __restrict__ inc, float* __restrict__ out_inc,
    unsigned short* __restrict__ Wneg, float* __restrict__ crow,
    const float* __restrict__ pre, unsigned short* __restrict__ preT,
    const float* __restrict__ r_proj, unsigned short* __restrict__ rprojT,
    const float* __restrict__ cur, unsigned short* __restrict__ curbf,
    float* __restrict__ out_loss) {
    __shared__ unsigned short tile[64 * 68];
    __shared__ float smax[4], ssum[4];
    const int bid = blockIdx.x;
    const int t = threadIdx.x;

    if (bid < 2048) {
        if (bid == 0 && t < 32) out_loss[t] = 0.f;
        const int row = bid;
        const float4* src = (const float4*)(inc + (size_t)row * 2048);
        float4* dst = (float4*)(out_inc + (size_t)row * 2048);
        ushort4* wp = (ushort4*)(Wneg + (size_t)row * 2048);
        float lmax = 0.f, ss = 0.f;
#pragma unroll
        for (int it = 0; it < 2; ++it) {
            int i = it * 256 + t;
            float4 v = src[i];
            dst[i] = v;
            float w0 = v.x > 0.01f ? v.x : 0.f;
            float w1 = v.y > 0.01f ? v.y : 0.f;
            float w2 = v.z > 0.01f ? v.z : 0.f;
            float w3 = v.w > 0.01f ? v.w : 0.f;
            ushort4 p;
            p.x = f2bf(-w0); p.y = f2bf(-w1); p.z = f2bf(-w2); p.w = f2bf(-w3);
            wp[i] = p;
            lmax = fmaxf(lmax, fmaxf(fmaxf(w0, w1), fmaxf(w2, w3)));
            ss += w0 * w0 + w1 * w1 + w2 * w2 + w3 * w3;
        }
#pragma unroll
        for (int off = 32; off; off >>= 1) {
            lmax = fmaxf(lmax, __shfl_down(lmax, off));
            ss += __shfl_down(ss, off);
        }
        int wv = t >> 6, ln = t & 63;
        if (ln == 0) { smax[wv] = lmax; ssum[wv] = ss; }
        __syncthreads();
        if (t == 0) {
            float m = fmaxf(fmaxf(smax[0], smax[1]), fmaxf(smax[2], smax[3]));
            float s = ssum[0] + ssum[1] + ssum[2] + ssum[3];
            crow[row] = m + 0.001f * sqrtf(s);
        }
    } else if (bid < 6144) {
        const int tt = bid - 2048;
        const int b = tt >> 7;
        const int mt = (tt & 127) >> 2;
        const int dt = tt & 3;
        transpose_64x64(pre + (size_t)b * 524288, preT + (size_t)b * 524288,
                        2048, 256, mt * 64, dt * 64, tile);
    } else if (bid < 6160) {
        const int tt = bid - 6144;
        transpose_64x64(r_proj, rprojT, 256, 256, (tt >> 2) * 64, (tt & 3) * 64,
                        tile);
    } else {
        // cur -> bf16: 2048 blocks x 256 thr x 32 f32
        const size_t base = (size_t)(bid - 6160) * 8192;
#pragma unroll
        for (int i = 0; i < 8; ++i) {
            size_t idx = base + (size_t)(i * 256 + t) * 4;
            float4 v = *(const float4*)(cur + idx);
            ushort4 p;
            p.x = f2bf(v.x); p.y = f2bf(v.y); p.z = f2bf(v.z); p.w = f2bf(v.w);
            *(ushort4*)(curbf + idx) = p;
        }
    }
}

// --------------------------------------------------------------------------
// gemm_diff: R7 core (best measured). Block = 256n x 256d, BK=32, 72 K-tiles
// (64 Wneg/preT + 8 curbf/rprojT). 32x32x16 MFMA, 16 waves (4m x 4n), wave
// tile 64x64 (acc f32x16[2][2], 4 waves/SIMD).
//
// Flat grid 256, XCD-aware remap: xcd = i&7, slot = i>>3, panel = slot&7,
// batch = xcd + 8*(slot>>3). XCD x: 8 panels x 4 batches; the 8 panels of a
// batch are adjacent slots -> preT tiles L2-shared within an XCD (dup 1x),
// Wneg panel read by 4 co-resident blocks.
//
// LDS: 4-deep rotation, per tile A(8KB)+B(8KB). Swizzle (64B rows, 4 x 16B
// chunks): LDS[r][p] = G[r][p ^ ((r>>1)&3)], read-side XOR q2.
// Pipeline: 3 tiles (6 loads/wave) in flight; per tile: vmcnt(4), s_barrier,
// stage(t+3), ks-loop. Drain at t=70/71 only.
//
// Epilogue: recon = sqrt(ssq); block-reduce 0.2*sum(recon) + sum(crow[panel])
// -> one atomicAdd into out_loss[b] (finalize kernel eliminated).
// --------------------------------------------------------------------------
__global__ __launch_bounds__(1024) void gemm_diff(
    const unsigned short* __restrict__ Wneg,    // (2048,2048) bf16 neg+masked
    const unsigned short* __restrict__ curbf,   // (32,2048,256) bf16
    const unsigned short* __restrict__ preT,    // (32,256,2048) bf16
    const unsigned short* __restrict__ rprojT,  // (256,256) bf16
    const float* __restrict__ crow,             // (2048)
    float* __restrict__ out_loss)               // (32)
{
    const int i    = blockIdx.x;                 // 0..255
    const int xcd  = i & 7;
    const int slot = i >> 3;                     // 0..31
    const int n0   = (slot & 7) * 256;           // panel
    const int b    = xcd + ((slot >> 3) << 3);   // batch

    __shared__ unsigned short Ab[4 * 256 * 32];  // 64 KB
    __shared__ unsigned short Bb[4 * 256 * 32];  // 64 KB
    __shared__ float ssq[256];
    __shared__ float red[16];

    const int tid  = threadIdx.x;
    const int w    = tid >> 6;                   // 0..15
    const int lane = tid & 63;
    const int l32  = lane & 31;
    const int half = lane >> 5;
    const int wm   = w >> 2;                     // n-band of 64
    const int wn   = w & 3;                      // d-band of 64
    const int w16  = w * 16;
    const int srow  = lane >> 2;                 // staging row within 16
    const int sbyte = ((lane & 3) ^ ((lane >> 3) & 3)) * 16;  // swizzled src
    const int q2    = (l32 >> 1) & 3;            // read-side swizzle

    if (tid < 256) ssq[tid] = 0.f;

    f32x16 acc[2][2] = {};

    const unsigned short* curA = curbf + (size_t)b * 2048 * 256 + (size_t)n0 * 256;
    const unsigned short* preB = preT + (size_t)b * 256 * 2048;
    const unsigned short* An   = Wneg + (size_t)n0 * 2048;

    // stage tile T (A 256x32 + B 256x32): 1+1 GLL16 per wave
#define STAGEPAIR(T, AB, AS, BB, BS, KK)                                       \
    {                                                                          \
        GLL16((const char*)((AB) + (size_t)(w16 + srow) * (AS) + (KK)) + sbyte,\
              (char*)Ab + ((T) & 3) * 16384 + w * 1024);                       \
        GLL16((const char*)((BB) + (size_t)(w16 + srow) * (BS) + (KK)) + sbyte,\
              (char*)Bb + ((T) & 3) * 16384 + w * 1024);                       \
    }

    // ---- prologue: tiles 0,1,2 in flight (6 loads/wave)
    STAGEPAIR(0, An, 2048, preB, 2048, 0);
    STAGEPAIR(1, An, 2048, preB, 2048, 32);
    STAGEPAIR(2, An, 2048, preB, 2048, 64);

    for (int t = 0; t < 72; ++t) {
        if (t < 70)       asm volatile("s_waitcnt vmcnt(4)" ::: "memory");
        else if (t == 70) asm volatile("s_waitcnt vmcnt(2)" ::: "memory");
        else              asm volatile("s_waitcnt vmcnt(0)" ::: "memory");
        asm volatile("s_barrier" ::: "memory");

        if (t < 69) {
            const int t3 = t + 3;
            const unsigned short *aB, *bB;
            int aS, bS, kk;
            if (t3 < 64) { aB = An;   aS = 2048; bB = preB;   bS = 2048; kk = t3 * 32; }
            else         { aB = curA; aS = 256;  bB = rprojT; bS = 256;  kk = (t3 - 64) * 32; }
            STAGEPAIR(t3, aB, aS, bB, bS, kk);
        }

        const unsigned short* Ac = Ab + (t & 3) * 8192;
        const unsigned short* Bc = Bb + (t & 3) * 8192;
#pragma unroll
        for (int ks = 0; ks < 2; ++ks) {
            const int co = (((ks << 1) + half) ^ q2) << 3;
            bf16x8 af[2], bfr[2];
#pragma unroll
            for (int mi = 0; mi < 2; ++mi)
                af[mi] = *(const bf16x8*)(Ac + (wm * 64 + mi * 32 + l32) * 32 + co);
#pragma unroll
            for (int ni = 0; ni < 2; ++ni)
                bfr[ni] = *(const bf16x8*)(Bc + (wn * 64 + ni * 32 + l32) * 32 + co);
#pragma unroll
            for (int mi = 0; mi < 2; ++mi)
#pragma unroll
                for (int ni = 0; ni < 2; ++ni)
                    acc[mi][ni] = __builtin_amdgcn_mfma_f32_32x32x16_bf16(
                        af[mi], bfr[ni], acc[mi][ni], 0, 0, 0);
        }
    }
    __syncthreads();

    // 32x32 C/D layout: col(d)=lane&31, row(n)=(reg&3)+8*(reg>>2)+4*half
#pragma unroll
    for (int mi = 0; mi < 2; ++mi)
#pragma unroll
        for (int reg = 0; reg < 16; ++reg) {
            float s = 0.f;
#pragma unroll
            for (int ni = 0; ni < 2; ++ni) {
                float v = acc[mi][ni][reg];
                s += v * v;
            }
            s += __shfl_xor(s, 1);
            s += __shfl_xor(s, 2);
            s += __shfl_xor(s, 4);
            s += __shfl_xor(s, 8);
            s += __shfl_xor(s, 16);
            if (l32 == 0) {
                const int row = wm * 64 + mi * 32 +
                                (reg & 3) + 8 * (reg >> 2) + 4 * half;
                atomicAdd(&ssq[row], s);  // 4-way (wn)
            }
        }
    __syncthreads();

    // epilogue reduce: 0.2*sum_n sqrt(ssq[n]) + sum_{n in panel} crow[n]
    float contrib = 0.f;
    if (tid < 256) contrib = 0.2f * sqrtf(ssq[tid]) + crow[n0 + tid];
#pragma unroll
    for (int off = 32; off; off >>= 1) contrib += __shfl_down(contrib, off);
    if (lane == 0) red[w] = contrib;
    __syncthreads();
    if (tid == 0) {
        float s = 0.f;
#pragma unroll
        for (int k = 0; k < 16; ++k) s += red[k];
        atomicAdd(out_loss + b, s);  // 8 adds per batch
    }
}

// --------------------------------------------------------------------------
extern "C" void kernel_launch(void* const* d_in, const int* in_sizes, int n_in,
                              void* d_out, int out_size, void* d_ws, size_t ws_size,
                              hipStream_t stream) {
    const float* cur    = (const float*)d_in[0];  // (32,2048,256)
    const float* pre    = (const float*)d_in[1];  // (32,2048,256)
    const float* r_proj = (const float*)d_in[2];  // (256,256)
    const float* inc    = (const float*)d_in[3];  // (2048,2048)
    float* out = (float*)d_out;                   // [0..31]=loss, [32..]=incidence

    char* ws = (char*)d_ws;
    unsigned short* Wneg   = (unsigned short*)(ws + 0);          //  8 MB
    unsigned short* preT   = (unsigned short*)(ws + 8388608);    // 32 MB
    unsigned short* rprojT = (unsigned short*)(ws + 41943040);   // 128 KB
    float*          crow   = (float*)(ws + 42336256);            // 8 KB
    unsigned short* curbf  = (unsigned short*)(ws + 42344448);   // 16 MB

    prep_all<<<8208, 256, 0, stream>>>(inc, out + 32, Wneg, crow,
                                       pre, preT, r_proj, rprojT,
                                       cur, curbf, out);
    gemm_diff<<<256, 1024, 0, stream>>>(Wneg, curbf, preT, rprojT, crow, out);
}